// Round 1
// baseline (512.814 us; speedup 1.0000x reference)
//
#include <hip/hip_runtime.h>

// Problem constants (match reference)
#define B_  32
#define C_  64
#define H_  64
#define W_  64
#define O_  128
#define LAT 64
#define HW  (H_*W_)
#define KJ  (O_*C_*9)   // 73728 columns of Wf

// ---------------------------------------------------------------------------
// Stage 1: global average pool  x[B,C,H,W] -> gap[B,C]
// grid = B*C blocks, 256 threads; each block reduces 4096 floats.
// ---------------------------------------------------------------------------
__global__ __launch_bounds__(256) void gap_kernel(const float* __restrict__ x,
                                                  float* __restrict__ gap) {
    int bc = blockIdx.x;                       // b*C_ + c
    const float4* p4 = (const float4*)(x + (size_t)bc * HW);
    int tid = threadIdx.x;
    float s = 0.f;
    #pragma unroll
    for (int i = 0; i < HW / 4 / 256; i++) {   // 4 iterations
        float4 v = p4[tid + i * 256];
        s += (v.x + v.y) + (v.z + v.w);
    }
    // wave64 reduce
    #pragma unroll
    for (int off = 32; off > 0; off >>= 1) s += __shfl_down(s, off);
    __shared__ float red[4];
    if ((tid & 63) == 0) red[tid >> 6] = s;
    __syncthreads();
    if (tid == 0) {
        float t = (red[0] + red[1]) + (red[2] + red[3]);
        gap[bc] = t * (1.0f / (float)HW);
    }
}

// ---------------------------------------------------------------------------
// Stage 2: two-layer MLP  f2 = relu(relu(gap@W1+b1)@W2+b2)
// grid = B blocks, 64 threads (one wave). Thread j owns output feature j.
// ---------------------------------------------------------------------------
__global__ __launch_bounds__(64) void mlp_kernel(const float* __restrict__ gap,
                                                 const float* __restrict__ W1,
                                                 const float* __restrict__ b1,
                                                 const float* __restrict__ W2,
                                                 const float* __restrict__ b2,
                                                 float* __restrict__ f2out) {
    int b = blockIdx.x, j = threadIdx.x;
    __shared__ float g[LAT], f1[LAT];
    g[j] = gap[b * LAT + j];
    __syncthreads();
    float acc = b1[j];
    #pragma unroll 8
    for (int l = 0; l < LAT; l++) acc = fmaf(g[l], W1[l * LAT + j], acc);
    f1[j] = fmaxf(acc, 0.f);
    __syncthreads();
    float acc2 = b2[j];
    #pragma unroll 8
    for (int l = 0; l < LAT; l++) acc2 = fmaf(f1[l], W2[l * LAT + j], acc2);
    f2out[b * LAT + j] = fmaxf(acc2, 0.f);
}

// ---------------------------------------------------------------------------
// Stage 3: kernel generator  ker[b][j] = f2[b]@Wf[:,j] + bf[j]
// Natural flat layout: j = ((o*C + c)*3 + kh)*3 + kw  (matches reference
// reshape), so ker is stored [b][o][c][3][3] fp32 in workspace.
// One thread per column j, all 32 batches accumulated in registers
// (Wf row values reused 32x; f2 reads are wave-uniform -> s_load).
// grid = KJ/256 = 288 blocks.
// ---------------------------------------------------------------------------
__global__ __launch_bounds__(256) void kergen_kernel(const float* __restrict__ f2,
                                                     const float* __restrict__ Wf,
                                                     const float* __restrict__ bf,
                                                     float* __restrict__ ker) {
    int j = blockIdx.x * 256 + threadIdx.x;
    float acc[B_];
    float base = bf[j];
    #pragma unroll
    for (int bb = 0; bb < B_; bb++) acc[bb] = base;
    #pragma unroll 4
    for (int l = 0; l < LAT; l++) {
        float w = Wf[(size_t)l * KJ + j];          // coalesced across threads
        #pragma unroll
        for (int bb = 0; bb < B_; bb++)
            acc[bb] = fmaf(f2[bb * LAT + l], w, acc[bb]);  // uniform -> s_load
    }
    #pragma unroll
    for (int bb = 0; bb < B_; bb++) ker[(size_t)bb * KJ + j] = acc[bb];
}

// ---------------------------------------------------------------------------
// Stage 4: per-sample 3x3 conv, 64 in-ch -> 128 out-ch, pad 1.
// out[b][o][h][w] = sum_{c,kh,kw} x[b][c][h+kh-1][w+kw-1] * ker[b][o][c][kh][kw]
// Block = 256 threads = 16x16 spatial tile, one pixel per thread.
// OT=8 output channels per thread (8 fp32 accumulators).
// Weights are wave-uniform per (oo,c,tap) -> scalar loads through K$.
// x 3x3 patch re-read per channel; per-c working set 1.3 KB -> L1 hits.
// grid = (16 spatial tiles, 16 o-tiles, 32 batches).
// ---------------------------------------------------------------------------
#define OT 8
__global__ __launch_bounds__(256) void conv_kernel(const float* __restrict__ x,
                                                   const float* __restrict__ ker,
                                                   float* __restrict__ out) {
    int b    = blockIdx.z;
    int o0   = blockIdx.y * OT;
    int tile = blockIdx.x;                       // 0..15 -> 4x4 spatial tiles
    int ty0 = (tile >> 2) * 16, tx0 = (tile & 3) * 16;
    int px = threadIdx.x & 15, py = threadIdx.x >> 4;
    int h = ty0 + py, w = tx0 + px;

    const float* xb = x + (size_t)b * C_ * HW;
    const float* kb = ker + ((size_t)b * O_ + o0) * (C_ * 9);

    // Per-tap validity (depends only on h,w; hoisted out of c-loop)
    bool okh[3], okw[3];
    #pragma unroll
    for (int d = 0; d < 3; d++) {
        okh[d] = (unsigned)(h + d - 1) < (unsigned)H_;
        okw[d] = (unsigned)(w + d - 1) < (unsigned)W_;
    }

    float acc[OT];
    #pragma unroll
    for (int i = 0; i < OT; i++) acc[i] = 0.f;

    for (int c = 0; c < C_; c++) {
        const float* xc = xb + c * HW;
        float xv[9];
        #pragma unroll
        for (int dy = 0; dy < 3; dy++) {
            #pragma unroll
            for (int dx = 0; dx < 3; dx++) {
                bool ok = okh[dy] && okw[dx];
                int hh = h + dy - 1, ww = w + dx - 1;
                xv[dy * 3 + dx] = ok ? xc[hh * W_ + ww] : 0.f;
            }
        }
        #pragma unroll
        for (int oo = 0; oo < OT; oo++) {
            const float* kk = kb + (oo * C_ + c) * 9;   // uniform -> s_load
            float a = acc[oo];
            #pragma unroll
            for (int t = 0; t < 9; t++) a = fmaf(xv[t], kk[t], a);
            acc[oo] = a;
        }
    }

    float* ob = out + ((size_t)b * O_ + o0) * HW + h * W_ + w;
    #pragma unroll
    for (int oo = 0; oo < OT; oo++) ob[oo * HW] = acc[oo];
}

// ---------------------------------------------------------------------------
// Launch
// ---------------------------------------------------------------------------
extern "C" void kernel_launch(void* const* d_in, const int* in_sizes, int n_in,
                              void* d_out, int out_size, void* d_ws, size_t ws_size,
                              hipStream_t stream) {
    const float* x  = (const float*)d_in[0];
    const float* W1 = (const float*)d_in[1];
    const float* b1 = (const float*)d_in[2];
    const float* W2 = (const float*)d_in[3];
    const float* b2 = (const float*)d_in[4];
    const float* Wf = (const float*)d_in[5];
    const float* bf = (const float*)d_in[6];
    float* out = (float*)d_out;

    // Workspace layout (fp32):
    //   gap : B*C      floats @ 0
    //   f2  : B*LAT    floats @ 8 KB
    //   ker : B*KJ     floats @ 16 KB   (9.44 MB)
    float* gap = (float*)d_ws;
    float* f2  = gap + 2048;
    float* ker = (float*)((char*)d_ws + 16384);

    gap_kernel<<<B_ * C_, 256, 0, stream>>>(x, gap);
    mlp_kernel<<<B_, 64, 0, stream>>>(gap, W1, b1, W2, b2, f2);
    kergen_kernel<<<KJ / 256, 256, 0, stream>>>(f2, Wf, bf, ker);
    conv_kernel<<<dim3(16, O_ / OT, B_), 256, 0, stream>>>(x, ker, out);
}

// Round 2
// 192.063 us; speedup vs baseline: 2.6700x; 2.6700x over previous
//
#include <hip/hip_runtime.h>

// Problem constants
#define B_  32
#define C_  64
#define H_  64
#define W_  64
#define O_  128
#define LAT 64
#define HW  (H_*W_)
#define KJ  (O_*C_*9)      // 73728
#define KTOT 576           // C_*9, GEMM K per batch

typedef __bf16 bf16x8 __attribute__((ext_vector_type(8)));
typedef float  f32x4  __attribute__((ext_vector_type(4)));

// ---------------------------------------------------------------------------
// Stage 0: zero the gap accumulator (ws is poisoned 0xAA before every launch)
// ---------------------------------------------------------------------------
__global__ void zero_gap(float* __restrict__ gap_acc) {
    gap_acc[blockIdx.x * 256 + threadIdx.x] = 0.f;
}

// ---------------------------------------------------------------------------
// Stage 1: fused transpose + GAP.
// Block per (b,h): transposes x[b][:][h][:] (64c x 64w fp32) into
// xT[b][h][w][c] bf16 (c contiguous), and atomically accumulates per-(b,c)
// row sums into gap_acc.
// ---------------------------------------------------------------------------
__global__ __launch_bounds__(256) void transpose_gap(const float* __restrict__ x,
                                                     __bf16* __restrict__ xT,
                                                     float* __restrict__ gap_acc) {
    int bh = blockIdx.x;
    int b = bh >> 6, h = bh & 63;
    __shared__ __bf16 lt[64 * 72];          // [w][c], c-stride padded to 72
    int t = threadIdx.x;
    int cbase = t >> 4;                      // 0..15
    int w4 = (t & 15) * 4;

    #pragma unroll
    for (int i = 0; i < 4; i++) {
        int cc = cbase + 16 * i;
        float4 v = *(const float4*)(x + (((size_t)(b * C_ + cc) * H_) + h) * W_ + w4);
        // transpose into LDS as bf16
        lt[(w4 + 0) * 72 + cc] = (__bf16)v.x;
        lt[(w4 + 1) * 72 + cc] = (__bf16)v.y;
        lt[(w4 + 2) * 72 + cc] = (__bf16)v.z;
        lt[(w4 + 3) * 72 + cc] = (__bf16)v.w;
        // per-(cc) partial sum over the 16 w4-lanes
        float s = (v.x + v.y) + (v.z + v.w);
        #pragma unroll
        for (int off = 8; off > 0; off >>= 1) s += __shfl_xor(s, off);
        if ((t & 15) == 0) atomicAdd(&gap_acc[b * C_ + cc], s);
    }
    __syncthreads();
    // coalesced write-out: 64 w x 8 c-chunks of 16B = 512 chunks
    const __bf16* src = lt;
    __bf16* dst = xT + ((size_t)(b * H_ + h) * W_) * C_;
    #pragma unroll
    for (int i = 0; i < 2; i++) {
        int chunk = t + i * 256;
        int w = chunk >> 3, c8 = chunk & 7;
        int4 v = *(const int4*)(src + w * 72 + c8 * 8);
        *(int4*)(dst + w * C_ + c8 * 8) = v;
    }
}

// ---------------------------------------------------------------------------
// Stage 2: two-layer MLP (fp32). One wave per batch.
// ---------------------------------------------------------------------------
__global__ __launch_bounds__(64) void mlp_kernel(const float* __restrict__ gap_acc,
                                                 const float* __restrict__ W1,
                                                 const float* __restrict__ b1,
                                                 const float* __restrict__ W2,
                                                 const float* __restrict__ b2,
                                                 float* __restrict__ f2out) {
    int b = blockIdx.x, j = threadIdx.x;
    __shared__ float g[LAT], f1[LAT];
    g[j] = gap_acc[b * LAT + j] * (1.0f / (float)HW);
    __syncthreads();
    float acc = b1[j];
    #pragma unroll 8
    for (int l = 0; l < LAT; l++) acc = fmaf(g[l], W1[l * LAT + j], acc);
    f1[j] = fmaxf(acc, 0.f);
    __syncthreads();
    float acc2 = b2[j];
    #pragma unroll 8
    for (int l = 0; l < LAT; l++) acc2 = fmaf(f1[l], W2[l * LAT + j], acc2);
    f2out[b * LAT + j] = fmaxf(acc2, 0.f);
}

// ---------------------------------------------------------------------------
// Stage 3: kernel generator -> bf16, tap-major layout kbf[b][o][tap][c].
// Wf column j = o*576 + c*9 + tap  (reference reshape (b,O,C,3,3)).
// Thread per column j (coalesced Wf reads), 32 batches in registers.
// ---------------------------------------------------------------------------
__global__ __launch_bounds__(256) void kergen_kernel(const float* __restrict__ f2,
                                                     const float* __restrict__ Wf,
                                                     const float* __restrict__ bf,
                                                     __bf16* __restrict__ kbf) {
    int j = blockIdx.x * 256 + threadIdx.x;
    float acc[B_];
    float base = bf[j];
    #pragma unroll
    for (int bb = 0; bb < B_; bb++) acc[bb] = base;
    #pragma unroll 4
    for (int l = 0; l < LAT; l++) {
        float w = Wf[(size_t)l * KJ + j];
        #pragma unroll
        for (int bb = 0; bb < B_; bb++)
            acc[bb] = fmaf(f2[bb * LAT + l], w, acc[bb]);
    }
    int o = j / KTOT;
    int rem = j - o * KTOT;
    int c = rem / 9;
    int tap = rem - c * 9;
    size_t dbase = (size_t)o * KTOT + tap * 64 + c;
    #pragma unroll
    for (int bb = 0; bb < B_; bb++)
        kbf[(size_t)bb * KJ + dbase] = (__bf16)acc[bb];
}

// ---------------------------------------------------------------------------
// Stage 4: implicit-GEMM MFMA conv.
// Per block: batch b, pixel tile = rows [h0,h0+1] x all 64 w (N=128), M=128 o.
// K = 576 = 9 taps x 64 c = 18 mfma_16x16x32 k-steps.
// LDS: xs[r=0..3][w'=0..65][c], c-stride padded 64->72 (2-way bank = free),
//      w' has zero halo at 0 and 65. A (ker) streamed from global (L2-hot),
//      register double-buffered.
// ---------------------------------------------------------------------------
#define CPAD 72
#define XS_ELEMS (4 * 66 * CPAD)    // 19008 elems = 38016 B

__global__ __launch_bounds__(256, 4) void conv_mfma(const __bf16* __restrict__ xT,
                                                    const __bf16* __restrict__ kbf,
                                                    float* __restrict__ out) {
    int b  = blockIdx.y;
    int h0 = blockIdx.x * 2;
    __shared__ __bf16 xs[XS_ELEMS];
    int tid = threadIdx.x;

    // zero-fill (covers halo + OOB rows)
    for (int i = tid; i < XS_ELEMS / 8; i += 256)
        ((int4*)xs)[i] = int4{0, 0, 0, 0};
    __syncthreads();

    // stage slab rows h0-1 .. h0+2 from xT (16B chunks, coalesced)
    #pragma unroll
    for (int i = 0; i < 8; i++) {
        int chunk = tid + i * 256;               // ((r*64)+w)*8 + c8
        int c8 = chunk & 7, w = (chunk >> 3) & 63, r = chunk >> 9;
        int hh = h0 - 1 + r;
        if ((unsigned)hh < (unsigned)H_) {
            int4 v = *(const int4*)(xT + ((size_t)(b * H_ + hh) * W_ + w) * C_ + c8 * 8);
            *(int4*)(xs + (r * 66 + w + 1) * CPAD + c8 * 8) = v;
        }
    }
    __syncthreads();

    int wave = tid >> 6, lane = tid & 63;
    int wi = wave >> 1, wj = wave & 1;           // 2x2 wave grid
    int l15 = lane & 15, quad = lane >> 4;

    // A: ker rows o = wi*64 + mt*16 + l15; frag k-offset = ks*32 + quad*8
    const __bf16* Abase = kbf + ((size_t)b * O_ + wi * 64 + l15) * KTOT + quad * 8;

    f32x4 acc[4][4];
    #pragma unroll
    for (int mt = 0; mt < 4; mt++)
        #pragma unroll
        for (int nt = 0; nt < 4; nt++)
            acc[mt][nt] = (f32x4){0.f, 0.f, 0.f, 0.f};

    bf16x8 Acur[4], Anext[4];
    #pragma unroll
    for (int mt = 0; mt < 4; mt++)
        Acur[mt] = *(const bf16x8*)(Abase + mt * 16 * KTOT);

    #pragma unroll
    for (int ks = 0; ks < 18; ks++) {
        // prefetch next A k-step (global, L2-hot)
        if (ks < 17) {
            #pragma unroll
            for (int mt = 0; mt < 4; mt++)
                Anext[mt] = *(const bf16x8*)(Abase + mt * 16 * KTOT + (ks + 1) * 32);
        }
        int tap = ks >> 1;                       // compile-time (loop unrolled)
        int kh = tap / 3, kw = tap - kh * 3;
        int c0 = (ks & 1) * 32;
        const __bf16* Bb = xs + ((wj + kh) * 66 + kw + l15) * CPAD + c0 + quad * 8;
        #pragma unroll
        for (int nt = 0; nt < 4; nt++) {
            bf16x8 bfrag = *(const bf16x8*)(Bb + nt * 16 * CPAD);
            #pragma unroll
            for (int mt = 0; mt < 4; mt++)
                acc[mt][nt] = __builtin_amdgcn_mfma_f32_16x16x32_bf16(
                    Acur[mt], bfrag, acc[mt][nt], 0, 0, 0);
        }
        #pragma unroll
        for (int mt = 0; mt < 4; mt++) Acur[mt] = Anext[mt];
    }

    // epilogue: D row = quad*4 + reg, col = l15
    int h = h0 + wj;
    float* ob = out + ((size_t)b * O_ + wi * 64) * HW + h * W_;
    #pragma unroll
    for (int mt = 0; mt < 4; mt++) {
        #pragma unroll
        for (int nt = 0; nt < 4; nt++) {
            int w = nt * 16 + l15;
            #pragma unroll
            for (int r = 0; r < 4; r++) {
                int oo = mt * 16 + quad * 4 + r;
                ob[(size_t)oo * HW + w] = acc[mt][nt][r];
            }
        }
    }
}

// ---------------------------------------------------------------------------
// Launch
// ---------------------------------------------------------------------------
extern "C" void kernel_launch(void* const* d_in, const int* in_sizes, int n_in,
                              void* d_out, int out_size, void* d_ws, size_t ws_size,
                              hipStream_t stream) {
    const float* x  = (const float*)d_in[0];
    const float* W1 = (const float*)d_in[1];
    const float* b1 = (const float*)d_in[2];
    const float* W2 = (const float*)d_in[3];
    const float* b2 = (const float*)d_in[4];
    const float* Wf = (const float*)d_in[5];
    const float* bf = (const float*)d_in[6];
    float* out = (float*)d_out;

    // Workspace layout:
    //   gap_acc : 2048 f32          @ 0
    //   f2      : 2048 f32          @ 8 KB
    //   kbf     : 32*73728 bf16     @ 16 KB        (4.72 MB)
    //   xT      : 32*64*64*64 bf16  @ 16 KB + 5 MB (16.8 MB)
    float*  gap_acc = (float*)d_ws;
    float*  f2      = gap_acc + 2048;
    __bf16* kbf     = (__bf16*)((char*)d_ws + 16384);
    __bf16* xT      = (__bf16*)((char*)d_ws + 16384 + ((size_t)B_ * KJ * 2 + 4096));

    zero_gap<<<8, 256, 0, stream>>>(gap_acc);
    transpose_gap<<<B_ * H_, 256, 0, stream>>>(x, xT, gap_acc);
    mlp_kernel<<<B_, 64, 0, stream>>>(gap_acc, W1, b1, W2, b2, f2);
    kergen_kernel<<<KJ / 256, 256, 0, stream>>>(f2, Wf, bf, kbf);
    conv_mfma<<<dim3(32, B_), 256, 0, stream>>>(xT, kbf, out);
}